// Round 1
// baseline (196.437 us; speedup 1.0000x reference)
//
#include <hip/hip_runtime.h>
#include <cstdint>
#include <cstddef>

// Problem constants
#define BB 2
#define TT 2048
#define DMODEL 1024
#define NHEADS 16
#define DK 64

typedef short short8 __attribute__((ext_vector_type(8)));
typedef unsigned short ushort8 __attribute__((ext_vector_type(8)));
typedef float floatx4 __attribute__((ext_vector_type(4)));
typedef _Float16 half4 __attribute__((ext_vector_type(4)));

// gfx950 f16 MFMA 16x16x16: A/B = 4xf16 (2 VGPR), C/D = 4xf32
#define MFMA_PV(A, B, C) __builtin_amdgcn_mfma_f32_16x16x16f16(A, B, C, 0, 0, 0)

// ---------- helpers ----------
__device__ __forceinline__ unsigned short f2bf(float f) {
    uint32_t u = __builtin_bit_cast(uint32_t, f);
    uint32_t r = (u + 0x7FFFu + ((u >> 16) & 1u)) >> 16;
    return (unsigned short)r;
}
__device__ __forceinline__ float bf2f(unsigned short s) {
    uint32_t u = ((uint32_t)s) << 16;
    return __builtin_bit_cast(float, u);
}

#define GLDS16(g, l) __builtin_amdgcn_global_load_lds( \
    (const __attribute__((address_space(1))) void*)(g), \
    (__attribute__((address_space(3))) void*)(l), 16, 0, 0)

// ---------- merged cast fp32 -> bf16 for x, w_qkv, w_out (one launch) ----------
__global__ void castk3(const float* __restrict__ x, unsigned short* __restrict__ xb,
                       const float* __restrict__ wq, unsigned short* __restrict__ wqb,
                       const float* __restrict__ wo, unsigned short* __restrict__ wob) {
    int bid = blockIdx.x;
    const float* in;
    unsigned short* out;
    int base;
    if (bid < 4096)       { in = x;  out = xb;  base = bid * 1024; }
    else if (bid < 7168)  { in = wq; out = wqb; base = (bid - 4096) * 1024; }
    else                  { in = wo; out = wob; base = (bid - 7168) * 1024; }
    int i = base + threadIdx.x * 4;
    float4 v = *(const float4*)(in + i);
    ushort4 o;
    o.x = f2bf(v.x); o.y = f2bf(v.y); o.z = f2bf(v.z); o.w = f2bf(v.w);
    *(ushort4*)(out + i) = o;
}

// ---------- bf16 MFMA GEMM, C = A * B^T, BK=32 (R10-proven: 0 conflicts) ----------
// A: [M][K], B: [N][K]. OUT = float (fp32 C) or unsigned short (bf16 C).
// Kept for the output projection (grid 256 blocks there).
template <typename OUT>
__global__ __launch_bounds__(256)
void gemm_bt(const unsigned short* __restrict__ A, const unsigned short* __restrict__ B,
             OUT* __restrict__ C, int M, int N, int K) {
    __shared__ unsigned short As[128 * 32];
    __shared__ unsigned short Bs[128 * 32];

    const int tid  = threadIdx.x;
    const int lane = tid & 63;
    const int w    = tid >> 6;
    const int wm   = w & 1;
    const int wn   = w >> 1;
    const int quad = lane >> 4;
    const int l16  = lane & 15;

    const int m0 = blockIdx.y * 128;
    const int n0 = blockIdx.x * 128;

    floatx4 acc[4][4];
#pragma unroll
    for (int a = 0; a < 4; a++)
#pragma unroll
        for (int b = 0; b < 4; b++)
            acc[a][b] = (floatx4){0.f, 0.f, 0.f, 0.f};

    const int c0 = w * 128 + lane;
    const int c1 = c0 + 64;
    const int r0 = c0 >> 2, cc0 = (c0 & 3) ^ ((r0 >> 1) & 3);
    const int r1 = c1 >> 2, cc1 = (c1 & 3) ^ ((r1 >> 1) & 3);

    const unsigned short* gA0 = A + (size_t)(m0 + r0) * K + cc0 * 8;
    const unsigned short* gA1 = A + (size_t)(m0 + r1) * K + cc1 * 8;
    const unsigned short* gB0 = B + (size_t)(n0 + r0) * K + cc0 * 8;
    const unsigned short* gB1 = B + (size_t)(n0 + r1) * K + cc1 * 8;

    unsigned short* lA0 = &As[(2 * w + 0) * 512];
    unsigned short* lA1 = &As[(2 * w + 1) * 512];
    unsigned short* lB0 = &Bs[(2 * w + 0) * 512];
    unsigned short* lB1 = &Bs[(2 * w + 1) * 512];

    const int rsw = (l16 >> 1) & 3;

    for (int k0 = 0; k0 < K; k0 += 32) {
        __syncthreads();
        GLDS16(gA0 + k0, lA0);
        GLDS16(gA1 + k0, lA1);
        GLDS16(gB0 + k0, lB0);
        GLDS16(gB1 + k0, lB1);
        __syncthreads();

        short8 af[4], bf[4];
#pragma unroll
        for (int t = 0; t < 4; t++) {
            af[t] = *(const short8*)&As[(wm * 64 + t * 16 + l16) * 32 + (quad ^ rsw) * 8];
            bf[t] = *(const short8*)&Bs[(wn * 64 + t * 16 + l16) * 32 + (quad ^ rsw) * 8];
        }
#pragma unroll
        for (int tm = 0; tm < 4; tm++)
#pragma unroll
            for (int tn = 0; tn < 4; tn++)
                acc[tm][tn] = __builtin_amdgcn_mfma_f32_16x16x32_bf16(
                    af[tm], bf[tn], acc[tm][tn], 0, 0, 0);
    }

#pragma unroll
    for (int tm = 0; tm < 4; tm++) {
#pragma unroll
        for (int tn = 0; tn < 4; tn++) {
#pragma unroll
            for (int r = 0; r < 4; r++) {
                int m = m0 + wm * 64 + tm * 16 + quad * 4 + r;
                int n = n0 + wn * 64 + tn * 16 + l16;
                if constexpr (sizeof(OUT) == 4)
                    C[(size_t)m * N + n] = acc[tm][tn][r];
                else
                    C[(size_t)m * N + n] = f2bf(acc[tm][tn][r]);
            }
        }
    }
}

// ---------- deep-pipelined 256x256 bf16 GEMM, C = A * B^T, bf16 out ----------
// 512 threads = 8 waves (2M x 4N), per-wave 128x64 output (acc[8][4]).
// BK=32, 4-deep LDS ring buffer (128 KiB), staged 3 tiles ahead via
// global_load_lds with the proven chunk-XOR swizzle (pre-swizzled global src,
// linear LDS dest). Counted s_waitcnt vmcnt(8) once per tile — never 0 in the
// main loop (T3+T4); s_setprio(1) around each 16-MFMA cluster (T5).
//
// Pipeline invariants:
//  - tile t lives in slot t&3; stage of tile t+3 is issued during tile t
//    (A-half at phase 0, B-half at phase 1), i.e. into the slot last read at
//    tile t-1 — safe, because the issue sits after the end-of-(t-1) barrier.
//  - vmcnt(8) at tile t leaves only tiles t+2,t+3 (8 loads) outstanding, so
//    tile t+1 is fully in LDS before its phase-0 ds_reads.
__global__ __launch_bounds__(512)
void gemm256(const unsigned short* __restrict__ A, const unsigned short* __restrict__ B,
             unsigned short* __restrict__ C, int M, int N, int K) {
    __shared__ unsigned short As[4][8192];   // [slot][256 rows x 32 cols]
    __shared__ unsigned short Bs[4][8192];

    const int tid  = threadIdx.x;
    const int lane = tid & 63;
    const int w    = tid >> 6;
    const int wm   = w >> 2;          // 0..1
    const int wn   = w & 3;           // 0..3
    const int quad = lane >> 4;
    const int l16  = lane & 15;

    const int m0 = blockIdx.y * 256;
    const int n0 = blockIdx.x * 256;

    floatx4 acc[8][4];
#pragma unroll
    for (int a = 0; a < 8; a++)
#pragma unroll
        for (int b = 0; b < 4; b++)
            acc[a][b] = (floatx4){0.f, 0.f, 0.f, 0.f};

    // staging addresses: thread tid stages LDS rows (tid>>2) and 128+(tid>>2),
    // physical chunk tid&3  <-  logical chunk (tid&3)^((tid>>3)&3)
    const int rA = tid >> 2;
    const int cA = (tid & 3) ^ ((tid >> 3) & 3);
    const unsigned short* gA0 = A + (size_t)(m0 + rA) * K + cA * 8;
    const unsigned short* gA1 = gA0 + (size_t)128 * K;
    const unsigned short* gB0 = B + (size_t)(n0 + rA) * K + cA * 8;
    const unsigned short* gB1 = gB0 + (size_t)128 * K;

    const int NT = K >> 5;

    // prologue: stage tiles 0,1,2 (issue order per tile: A then B)
    GLDS16(gA0,      &As[0][w * 512]);
    GLDS16(gA1,      &As[0][4096 + w * 512]);
    GLDS16(gB0,      &Bs[0][w * 512]);
    GLDS16(gB1,      &Bs[0][4096 + w * 512]);
    GLDS16(gA0 + 32, &As[1][w * 512]);
    GLDS16(gA1 + 32, &As[1][4096 + w * 512]);
    GLDS16(gB0 + 32, &Bs[1][w * 512]);
    GLDS16(gB1 + 32, &Bs[1][4096 + w * 512]);
    GLDS16(gA0 + 64, &As[2][w * 512]);
    GLDS16(gA1 + 64, &As[2][4096 + w * 512]);
    GLDS16(gB0 + 64, &Bs[2][w * 512]);
    GLDS16(gB1 + 64, &Bs[2][4096 + w * 512]);
    asm volatile("s_waitcnt vmcnt(8)" ::: "memory");   // tile 0 landed
    __builtin_amdgcn_s_barrier();

    const int rsw  = (l16 >> 1) & 3;
    const int aoff = (wm * 128 + l16) * 32 + ((quad ^ rsw) * 8);
    const int boff = (wn * 64  + l16) * 32 + ((quad ^ rsw) * 8);

#define TILE_BODY(IT, DO_STAGE, VMWAIT)                                         \
    {                                                                           \
        const int s_ = (IT) & 3;                                                \
        short8 bfr[4], afr[4];                                                  \
        _Pragma("unroll")                                                       \
        for (int nf = 0; nf < 4; nf++)                                          \
            bfr[nf] = *(const short8*)&Bs[s_][boff + nf * 512];                 \
        _Pragma("unroll")                                                       \
        for (int mf = 0; mf < 4; mf++)                                          \
            afr[mf] = *(const short8*)&As[s_][aoff + mf * 512];                 \
        if (DO_STAGE) {                                                         \
            const int sn_ = ((IT) + 3) & 3;                                     \
            GLDS16(gA0 + ((IT) + 3) * 32, &As[sn_][w * 512]);                   \
            GLDS16(gA1 + ((IT) + 3) * 32, &As[sn_][4096 + w * 512]);            \
        }                                                                       \
        __builtin_amdgcn_s_barrier();                                           \
        asm volatile("s_waitcnt lgkmcnt(0)" ::: "memory");                      \
        __builtin_amdgcn_s_setprio(1);                                          \
        _Pragma("unroll")                                                       \
        for (int mf = 0; mf < 4; mf++)                                          \
            _Pragma("unroll")                                                   \
            for (int nf = 0; nf < 4; nf++)                                      \
                acc[mf][nf] = __builtin_amdgcn_mfma_f32_16x16x32_bf16(          \
                    afr[mf], bfr[nf], acc[mf][nf], 0, 0, 0);                    \
        __builtin_amdgcn_s_setprio(0);                                          \
        __builtin_amdgcn_s_barrier();                                           \
        _Pragma("unroll")                                                       \
        for (int mf = 0; mf < 4; mf++)                                          \
            afr[mf] = *(const short8*)&As[s_][aoff + (4 + mf) * 512];           \
        if (DO_STAGE) {                                                         \
            const int sn_ = ((IT) + 3) & 3;                                     \
            GLDS16(gB0 + ((IT) + 3) * 32, &Bs[sn_][w * 512]);                   \
            GLDS16(gB1 + ((IT) + 3) * 32, &Bs[sn_][4096 + w * 512]);            \
        }                                                                       \
        asm volatile(VMWAIT ::: "memory");                                      \
        __builtin_amdgcn_s_barrier();                                           \
        asm volatile("s_waitcnt lgkmcnt(0)" ::: "memory");                      \
        __builtin_amdgcn_s_setprio(1);                                          \
        _Pragma("unroll")                                                       \
        for (int mf = 0; mf < 4; mf++)                                          \
            _Pragma("unroll")                                                   \
            for (int nf = 0; nf < 4; nf++)                                      \
                acc[4 + mf][nf] = __builtin_amdgcn_mfma_f32_16x16x32_bf16(      \
                    afr[mf], bfr[nf], acc[4 + mf][nf], 0, 0, 0);                \
        __builtin_amdgcn_s_setprio(0);                                          \
        __builtin_amdgcn_s_barrier();                                           \
    }

    for (int it = 0; it < NT - 3; ++it)
        TILE_BODY(it, 1, "s_waitcnt vmcnt(8)");
    TILE_BODY(NT - 3, 0, "s_waitcnt vmcnt(4)");
    TILE_BODY(NT - 2, 0, "s_waitcnt vmcnt(0)");
    TILE_BODY(NT - 1, 0, "s_waitcnt vmcnt(0)");
#undef TILE_BODY

    // epilogue: bf16 C write
#pragma unroll
    for (int mf = 0; mf < 8; mf++) {
#pragma unroll
        for (int nf = 0; nf < 4; nf++) {
#pragma unroll
            for (int r = 0; r < 4; r++) {
                int m = m0 + wm * 128 + mf * 16 + quad * 4 + r;
                int n = n0 + wn * 64 + nf * 16 + l16;
                C[(size_t)m * N + n] = f2bf(acc[mf][nf][r]);
            }
        }
    }
}

// ---------- fused RoPE split + V transpose, bf16 qkv input ----------
// Block: 64 t-rows of one head. Part 1: rope q,k -> qb,kb bf16 [B*H][T][64]
// (q pre-scaled by 0.125*log2(e)). Part 2: v -> vtb f16 [B*H][64][T] with the
// odd-row 8B half-swap (kills attn's phase-local V bank conflicts).
__global__ __launch_bounds__(256)
void ropevt(const unsigned short* __restrict__ qkv,
            unsigned short* __restrict__ qb, unsigned short* __restrict__ kb,
            unsigned short* __restrict__ vtb) {
    __shared__ unsigned short tile[64][72];   // V slice, bf16
    const int tid = threadIdx.x;
    const int bh  = blockIdx.y;
    const int b = bh >> 4, h = bh & 15;
    const int t0 = blockIdx.x * 64;

    // ---- RoPE for q,k: 64 rows x 32 pairs = 2048 pairs, 8 per thread ----
    const float QS = 0.18033688f;   // 0.125 * log2(e)
#pragma unroll
    for (int rep = 0; rep < 8; rep++) {
        int idx  = rep * 256 + tid;
        int p    = idx & 31;
        int trow = idx >> 5;
        int t    = t0 + trow;

        size_t src = (size_t)(b * TT + t) * 3072 + h * 64 + 2 * p;
        ushort2 qu = *(const ushort2*)(qkv + src);
        ushort2 ku = *(const ushort2*)(qkv + src + 1024);
        float qx = bf2f(qu.x), qy = bf2f(qu.y);
        float kx = bf2f(ku.x), ky = bf2f(ku.y);

        float invf = __powf(10000.f, -((float)(2 * p)) / 64.f);
        float ang  = (float)t * invf;
        float sn, cs;
        __sincosf(ang, &sn, &cs);

        size_t dst = ((size_t)bh * TT + t) * 64 + 2 * p;
        ushort2 qo, ko;
        qo.x = f2bf((qx * cs - qy * sn) * QS); qo.y = f2bf((qy * cs + qx * sn) * QS);
        ko.x = f2bf(kx * cs - ky * sn); ko.y = f2bf(ky * cs + kx * sn);
        *(ushort2*)(qb + dst) = qo;
        *(ushort2*)(kb + dst) = ko;
    }

    // ---- V transpose (bf16 in, f16 out) ----
    const int row = tid >> 2;
    const unsigned short* src = qkv + ((size_t)(b * TT) + t0 + row) * 3072 + 2048 + h * 64;
    {
        int cb = (tid & 3) * 16;                        // 16 cols per thread
        ushort8 v0 = *(const ushort8*)(src + cb);
        ushort8 v1 = *(const ushort8*)(src + cb + 8);
#pragma unroll
        for (int i = 0; i < 8; i++) tile[row][cb + i] = v0[i];
#pragma unroll
        for (int i = 0; i < 8; i++) tile[row][cb + 8 + i] = v1[i];
    }
    __syncthreads();

    const int d  = tid >> 2;
    const int tc = tid & 3;
    const int hs = (d & 1) * 4;       // half-swap for odd rows
    ushort8 o0, o1;
#pragma unroll
    for (int i = 0; i < 8; i++) {
        _Float16 hv = (_Float16)bf2f(tile[tc * 16 + (i ^ hs)][d]);
        o0[i] = __builtin_bit_cast(unsigned short, hv);
    }
#pragma unroll
    for (int i = 0; i < 8; i++) {
        _Float16 hv = (_Float16)bf2f(tile[tc * 16 + 8 + (i ^ hs)][d]);
        o1[i] = __builtin_bit_cast(unsigned short, hv);
    }
    unsigned short* dst = vtb + ((size_t)bh * 64 + d) * TT + t0 + tc * 16;
    *(ushort8*)(dst) = o0;
    *(ushort8*)(dst + 8) = o1;
}

// ---------- MFMA flash attention (causal): transposed-S + double-buffered LDS ----------
__global__ __launch_bounds__(256, 5)
void attn_mfma(const unsigned short* __restrict__ qb,
               const unsigned short* __restrict__ kb,
               const unsigned short* __restrict__ vtb,
               unsigned short* __restrict__ out) {
    __shared__ unsigned short Ks[2][64 * 64];   // [t][d] bf16, chunk-swizzled
    __shared__ unsigned short Vs[2][64 * 64];   // [d][t] f16,  chunk-swizzled + half-swapped

    const int tid  = threadIdx.x;
    const int lane = tid & 63;
    const int w    = tid >> 6;
    const int quad = lane >> 4;
    const int l16  = lane & 15;

    const int bh    = blockIdx.x;                    // head pinned to one XCD (32 % 8)
    const int qtile = gridDim.y - 1 - blockIdx.y;    // longest first
    const int q0    = qtile * 64;

    const unsigned short* Qp = qb + ((size_t)bh * TT + q0 + w * 16) * 64;
    const unsigned short* Kp = kb + (size_t)bh * TT * 64;
    const unsigned short* Vp = vtb + (size_t)bh * 64 * TT;   // f16 bits in ushort

    short8 aq[2];
#pragma unroll
    for (int ks = 0; ks < 2; ks++)
        aq[ks] = *(const short8*)(Qp + (size_t)l16 * 64 + ks * 32 + quad * 8);

    floatx4 Oacc[4];   // O^T: row d = dt*16 + quad*4 + r, col q = l16
#pragma unroll
    for (int dt = 0; dt < 4; dt++) Oacc[dt] = (floatx4){0.f, 0.f, 0.f, 0.f};
    float m = -1e30f, l = 0.f;

    const int ntiles = qtile + 1;

#define STAGE(IT, P)                                                                      \
    {                                                                                     \
        const int j0s = (IT) * 64;                                                        \
        _Pragma("unroll")                                                                 \
        for (int rep = 0; rep < 2; rep++) {                                               \
            int c    = rep * 256 + tid;                                                   \
            int row  = c >> 3, sl = c & 7;                                                \
            GLDS16(Kp + (size_t)(j0s + row) * 64 + (sl ^ (row & 7)) * 8, &Ks[P][c * 8]);  \
            GLDS16(Vp + (size_t)row * TT + j0s + (sl ^ ((row >> 1) & 7)) * 8,             \
                   &Vs[P][c * 8]);                                                        \
        }                                                                                 \
    }

    STAGE(0, 0);
    __syncthreads();

    const int ksw = l16 & 7;
    const int vsw = (l16 >> 1) & 7;
    const int vsub = ((quad & 1) ^ (l16 & 1)) * 4;

    for (int it = 0; it < ntiles; ++it) {
        const int p = it & 1;
        if (it + 1 < ntiles) STAGE(it + 1, p ^ 1);

        floatx4 sacc[4];
#pragma unroll
        for (int nt = 0; nt < 4; nt++) sacc[nt] = (floatx4){0.f, 0.f, 0.f, 0.f};
#pragma unroll
        for (int ks = 0; ks < 2; ks++)
#pragma unroll
            for (int nt = 0; nt < 4; nt++) {
                short8 kf = *(const short8*)&Ks[p][(nt * 16 + l16) * 64 + ((ks * 4 + quad) ^ ksw) * 8];
                sacc[nt] = __builtin_amdgcn_mfma_f32_16x16x32_bf16(kf, aq[ks], sacc[nt], 0, 0, 0);
            }

        if (it == qtile) {
            const int qg = w * 16 + l16;
#pragma unroll
            for (int nt = 0; nt < 4; nt++)
#pragma unroll
                for (int r = 0; r < 4; r++)
                    if (nt * 16 + quad * 4 + r > qg) sacc[nt][r] = -1e30f;
        }

        float mx = sacc[0][0];
#pragma unroll
        for (int nt = 0; nt < 4; nt++)
#pragma unroll
            for (int r = 0; r < 4; r++) mx = fmaxf(mx, sacc[nt][r]);
        mx = fmaxf(mx, __shfl_xor(mx, 16));
        mx = fmaxf(mx, __shfl_xor(mx, 32));
        float mnew  = fmaxf(m, mx);
        float alpha = __builtin_amdgcn_exp2f(m - mnew);
        m = mnew;
        float psum = 0.f;
#pragma unroll
        for (int nt = 0; nt < 4; nt++)
#pragma unroll
            for (int r = 0; r < 4; r++) {
                float pv = __builtin_amdgcn_exp2f(sacc[nt][r] - mnew);
                sacc[nt][r] = pv;
                psum += pv;
            }
        psum += __shfl_xor(psum, 16);
        psum += __shfl_xor(psum, 32);
        l = l * alpha + psum;

#pragma unroll
        for (int dt = 0; dt < 4; dt++)
#pragma unroll
            for (int r = 0; r < 4; r++) Oacc[dt][r] *= alpha;

        half4 bp[4];
#pragma unroll
        for (int nt = 0; nt < 4; nt++) {
            half4 h;
            h[0] = (_Float16)sacc[nt][0];
            h[1] = (_Float16)sacc[nt][1];
            h[2] = (_Float16)sacc[nt][2];
            h[3] = (_Float16)sacc[nt][3];
            bp[nt] = h;
        }

#pragma unroll
        for (int dt = 0; dt < 4; dt++)
#pragma unroll
            for (int nt = 0; nt < 4; nt++) {
                int c = nt * 2 + (quad >> 1);
                half4 vf = *(const half4*)&Vs[p][(dt * 16 + l16) * 64 + (c ^ vsw) * 8 + vsub];
                Oacc[dt] = MFMA_PV(vf, bp[nt], Oacc[dt]);
            }

        __syncthreads();
    }
#undef STAGE

    const int b = bh >> 4, h = bh & 15;
    const float inv = 1.f / l;
    const size_t base = ((size_t)(b * TT + q0 + w * 16 + l16)) * DMODEL + h * 64 + quad * 4;
#pragma unroll
    for (int dt = 0; dt < 4; dt++) {
        ushort4 pk;
        pk.x = f2bf(Oacc[dt][0] * inv);
        pk.y = f2bf(Oacc[dt][1] * inv);
        pk.z = f2bf(Oacc[dt][2] * inv);
        pk.w = f2bf(Oacc[dt][3] * inv);
        *(ushort4*)(out + base + dt * 16) = pk;
    }
}

// ---------- launch ----------
extern "C" void kernel_launch(void* const* d_in, const int* in_sizes, int n_in,
                              void* d_out, int out_size, void* d_ws, size_t ws_size,
                              hipStream_t stream) {
    const float* x     = (const float*)d_in[0];   // [2,2048,1024]
    const float* w_qkv = (const float*)d_in[1];   // [3072,1024]
    const float* w_out = (const float*)d_in[2];   // [1024,1024]
    float* out = (float*)d_out;                   // [2,2048,1024]

    char* ws = (char*)d_ws;

    unsigned short* xb   = (unsigned short*)(ws);                 // 8 MB
    unsigned short* wqb  = (unsigned short*)(ws + 8388608);       // 6 MB
    unsigned short* wob  = (unsigned short*)(ws + 14680064);      // 2 MB
    unsigned short* qkvb = (unsigned short*)(ws + 16777216);      // 24 MB (bf16)
    unsigned short* qb   = (unsigned short*)(ws + 41943040);      // 8 MB
    unsigned short* kb   = (unsigned short*)(ws + 50331648);      // 8 MB
    unsigned short* vtb  = (unsigned short*)(ws + 58720256);      // 8 MB (f16)
    unsigned short* attb = (unsigned short*)(ws + 67108864);      // 8 MB

    castk3<<<8192, 256, 0, stream>>>(x, xb, w_qkv, wqb, w_out, wob);

    // qkv = x @ w_qkv^T   (M=4096, N=3072, K=1024), bf16 output
    // deep-pipelined 256x256 kernel: grid 12x16 = 192 blocks, 512 thr
    gemm256<<<dim3(3072 / 256, 4096 / 256), 512, 0, stream>>>(
        xb, wqb, qkvb, 4096, 3072, 1024);

    // fused rope + v-transpose (bf16 input)
    ropevt<<<dim3(TT / 64, BB * NHEADS), 256, 0, stream>>>(qkvb, qb, kb, vtb);

    // grid: x = bh (XCD locality), y = qtile (reversed in kernel: longest first)
    attn_mfma<<<dim3(BB * NHEADS, TT / 64), 256, 0, stream>>>(qb, kb, vtb, attb);

    // out = attn @ w_out^T (M=4096, N=1024, K=1024), fp32 output
    gemm_bt<float><<<dim3(1024 / 128, 4096 / 128), 256, 0, stream>>>(
        attb, wob, out, 4096, 1024, 1024);
}

// Round 2
// 191.952 us; speedup vs baseline: 1.0234x; 1.0234x over previous
//
#include <hip/hip_runtime.h>
#include <cstdint>
#include <cstddef>

// Problem constants
#define BB 2
#define TT 2048
#define DMODEL 1024
#define NHEADS 16
#define DK 64

typedef short short8 __attribute__((ext_vector_type(8)));
typedef unsigned short ushort8 __attribute__((ext_vector_type(8)));
typedef float floatx4 __attribute__((ext_vector_type(4)));
typedef _Float16 half4 __attribute__((ext_vector_type(4)));

// gfx950 f16 MFMA 16x16x16: A/B = 4xf16 (2 VGPR), C/D = 4xf32
#define MFMA_PV(A, B, C) __builtin_amdgcn_mfma_f32_16x16x16f16(A, B, C, 0, 0, 0)

// ---------- helpers ----------
__device__ __forceinline__ unsigned short f2bf(float f) {
    uint32_t u = __builtin_bit_cast(uint32_t, f);
    uint32_t r = (u + 0x7FFFu + ((u >> 16) & 1u)) >> 16;
    return (unsigned short)r;
}
__device__ __forceinline__ float bf2f(unsigned short s) {
    uint32_t u = ((uint32_t)s) << 16;
    return __builtin_bit_cast(float, u);
}

#define GLDS16(g, l) __builtin_amdgcn_global_load_lds( \
    (const __attribute__((address_space(1))) void*)(g), \
    (__attribute__((address_space(3))) void*)(l), 16, 0, 0)

// ---------- merged cast fp32 -> bf16 for x, w_qkv, w_out (one launch) ----------
__global__ void castk3(const float* __restrict__ x, unsigned short* __restrict__ xb,
                       const float* __restrict__ wq, unsigned short* __restrict__ wqb,
                       const float* __restrict__ wo, unsigned short* __restrict__ wob) {
    int bid = blockIdx.x;
    const float* in;
    unsigned short* out;
    int base;
    if (bid < 4096)       { in = x;  out = xb;  base = bid * 1024; }
    else if (bid < 7168)  { in = wq; out = wqb; base = (bid - 4096) * 1024; }
    else                  { in = wo; out = wob; base = (bid - 7168) * 1024; }
    int i = base + threadIdx.x * 4;
    float4 v = *(const float4*)(in + i);
    ushort4 o;
    o.x = f2bf(v.x); o.y = f2bf(v.y); o.z = f2bf(v.z); o.w = f2bf(v.w);
    *(ushort4*)(out + i) = o;
}

// ---------- bf16 MFMA GEMM, C = A * B^T, BK=32 (R10-proven: 0 conflicts) ----------
// A: [M][K], B: [N][K]. OUT = float (fp32 C) or unsigned short (bf16 C).
// Kept for the output projection (grid 256 blocks there = 1/CU).
template <typename OUT>
__global__ __launch_bounds__(256)
void gemm_bt(const unsigned short* __restrict__ A, const unsigned short* __restrict__ B,
             OUT* __restrict__ C, int M, int N, int K) {
    __shared__ unsigned short As[128 * 32];
    __shared__ unsigned short Bs[128 * 32];

    const int tid  = threadIdx.x;
    const int lane = tid & 63;
    const int w    = tid >> 6;
    const int wm   = w & 1;
    const int wn   = w >> 1;
    const int quad = lane >> 4;
    const int l16  = lane & 15;

    const int m0 = blockIdx.y * 128;
    const int n0 = blockIdx.x * 128;

    floatx4 acc[4][4];
#pragma unroll
    for (int a = 0; a < 4; a++)
#pragma unroll
        for (int b = 0; b < 4; b++)
            acc[a][b] = (floatx4){0.f, 0.f, 0.f, 0.f};

    const int c0 = w * 128 + lane;
    const int c1 = c0 + 64;
    const int r0 = c0 >> 2, cc0 = (c0 & 3) ^ ((r0 >> 1) & 3);
    const int r1 = c1 >> 2, cc1 = (c1 & 3) ^ ((r1 >> 1) & 3);

    const unsigned short* gA0 = A + (size_t)(m0 + r0) * K + cc0 * 8;
    const unsigned short* gA1 = A + (size_t)(m0 + r1) * K + cc1 * 8;
    const unsigned short* gB0 = B + (size_t)(n0 + r0) * K + cc0 * 8;
    const unsigned short* gB1 = B + (size_t)(n0 + r1) * K + cc1 * 8;

    unsigned short* lA0 = &As[(2 * w + 0) * 512];
    unsigned short* lA1 = &As[(2 * w + 1) * 512];
    unsigned short* lB0 = &Bs[(2 * w + 0) * 512];
    unsigned short* lB1 = &Bs[(2 * w + 1) * 512];

    const int rsw = (l16 >> 1) & 3;

    for (int k0 = 0; k0 < K; k0 += 32) {
        __syncthreads();
        GLDS16(gA0 + k0, lA0);
        GLDS16(gA1 + k0, lA1);
        GLDS16(gB0 + k0, lB0);
        GLDS16(gB1 + k0, lB1);
        __syncthreads();

        short8 af[4], bf[4];
#pragma unroll
        for (int t = 0; t < 4; t++) {
            af[t] = *(const short8*)&As[(wm * 64 + t * 16 + l16) * 32 + (quad ^ rsw) * 8];
            bf[t] = *(const short8*)&Bs[(wn * 64 + t * 16 + l16) * 32 + (quad ^ rsw) * 8];
        }
#pragma unroll
        for (int tm = 0; tm < 4; tm++)
#pragma unroll
            for (int tn = 0; tn < 4; tn++)
                acc[tm][tn] = __builtin_amdgcn_mfma_f32_16x16x32_bf16(
                    af[tm], bf[tn], acc[tm][tn], 0, 0, 0);
    }

#pragma unroll
    for (int tm = 0; tm < 4; tm++) {
#pragma unroll
        for (int tn = 0; tn < 4; tn++) {
#pragma unroll
            for (int r = 0; r < 4; r++) {
                int m = m0 + wm * 64 + tm * 16 + quad * 4 + r;
                int n = n0 + wn * 64 + tn * 16 + l16;
                if constexpr (sizeof(OUT) == 4)
                    C[(size_t)m * N + n] = acc[tm][tn][r];
                else
                    C[(size_t)m * N + n] = f2bf(acc[tm][tn][r]);
            }
        }
    }
}

// ---------- deep-pipelined 256x256 bf16 GEMM, C = A * B^T, bf16 out ----------
// v2: ONE barrier per K-tile (was 4). Ring distance 4, stage-to-use distance 3:
//  - stage into slot (t+3)&3 == (t-1)&3 sits right after the barrier ending
//    tile t-1 (all waves' reads of that slot consumed by their MFMAs before it)
//  - end-of-tile vmcnt(8)+s_barrier proves tile t+1 landed for ALL waves
//    (counted, never 0 mid-loop; epilogue drains 8->4->0)
// Plus bijective XCD swizzle (192 % 8 == 0) for L2 locality.
__global__ __launch_bounds__(512)
void gemm256(const unsigned short* __restrict__ A, const unsigned short* __restrict__ B,
             unsigned short* __restrict__ C, int M, int N, int K) {
    __shared__ unsigned short As[4][8192];   // [slot][256 rows x 32 cols]
    __shared__ unsigned short Bs[4][8192];

    const int tid  = threadIdx.x;
    const int lane = tid & 63;
    const int w    = tid >> 6;
    const int wm   = w >> 2;          // 0..1
    const int wn   = w & 3;           // 0..3
    const int quad = lane >> 4;
    const int l16  = lane & 15;

    // XCD-aware bijective swizzle (requires nwg % 8 == 0; 192 here)
    const int gx  = gridDim.x;
    const int bid = blockIdx.y * gx + blockIdx.x;
    const int cpx = (gx * gridDim.y) >> 3;
    const int wg  = (bid & 7) * cpx + (bid >> 3);
    const int m0  = (wg / gx) * 256;
    const int n0  = (wg % gx) * 256;

    floatx4 acc[8][4];
#pragma unroll
    for (int a = 0; a < 8; a++)
#pragma unroll
        for (int b = 0; b < 4; b++)
            acc[a][b] = (floatx4){0.f, 0.f, 0.f, 0.f};

    // staging: thread tid stages LDS rows (tid>>2) and 128+(tid>>2);
    // physical chunk tid&3  <-  logical chunk (tid&3)^((tid>>3)&3)
    const int rA = tid >> 2;
    const int cA = (tid & 3) ^ ((tid >> 3) & 3);
    const unsigned short* gA0 = A + (size_t)(m0 + rA) * K + cA * 8;
    const unsigned short* gA1 = gA0 + (size_t)128 * K;
    const unsigned short* gB0 = B + (size_t)(n0 + rA) * K + cA * 8;
    const unsigned short* gB1 = gB0 + (size_t)128 * K;

    const int NT = K >> 5;

    // prologue: stage tiles 0,1,2
    GLDS16(gA0,      &As[0][w * 512]);
    GLDS16(gA1,      &As[0][4096 + w * 512]);
    GLDS16(gB0,      &Bs[0][w * 512]);
    GLDS16(gB1,      &Bs[0][4096 + w * 512]);
    GLDS16(gA0 + 32, &As[1][w * 512]);
    GLDS16(gA1 + 32, &As[1][4096 + w * 512]);
    GLDS16(gB0 + 32, &Bs[1][w * 512]);
    GLDS16(gB1 + 32, &Bs[1][4096 + w * 512]);
    GLDS16(gA0 + 64, &As[2][w * 512]);
    GLDS16(gA1 + 64, &As[2][4096 + w * 512]);
    GLDS16(gB0 + 64, &Bs[2][w * 512]);
    GLDS16(gB1 + 64, &Bs[2][4096 + w * 512]);
    asm volatile("s_waitcnt vmcnt(8)" ::: "memory");   // tile 0 landed
    __builtin_amdgcn_s_barrier();
    __builtin_amdgcn_sched_barrier(0);

    const int rsw  = (l16 >> 1) & 3;
    const int aoff = (wm * 128 + l16) * 32 + ((quad ^ rsw) * 8);
    const int boff = (wn * 64  + l16) * 32 + ((quad ^ rsw) * 8);

#define TILE_BODY(IT, DO_STAGE, VMWAIT)                                         \
    {                                                                           \
        const int s_ = (IT) & 3;                                                \
        short8 bfr[4], afr[4];                                                  \
        _Pragma("unroll")                                                       \
        for (int nf = 0; nf < 4; nf++)                                          \
            bfr[nf] = *(const short8*)&Bs[s_][boff + nf * 512];                 \
        _Pragma("unroll")                                                       \
        for (int mf = 0; mf < 4; mf++)                                          \
            afr[mf] = *(const short8*)&As[s_][aoff + mf * 512];                 \
        if (DO_STAGE) {                                                         \
            const int sn_ = ((IT) + 3) & 3;                                     \
            GLDS16(gA0 + ((IT) + 3) * 32, &As[sn_][w * 512]);                   \
            GLDS16(gA1 + ((IT) + 3) * 32, &As[sn_][4096 + w * 512]);            \
        }                                                                       \
        __builtin_amdgcn_s_setprio(1);                                          \
        _Pragma("unroll")                                                       \
        for (int mf = 0; mf < 4; mf++)                                          \
            _Pragma("unroll")                                                   \
            for (int nf = 0; nf < 4; nf++)                                      \
                acc[mf][nf] = __builtin_amdgcn_mfma_f32_16x16x32_bf16(          \
                    afr[mf], bfr[nf], acc[mf][nf], 0, 0, 0);                    \
        __builtin_amdgcn_s_setprio(0);                                          \
        _Pragma("unroll")                                                       \
        for (int mf = 0; mf < 4; mf++)                                          \
            afr[mf] = *(const short8*)&As[s_][aoff + (4 + mf) * 512];           \
        if (DO_STAGE) {                                                         \
            const int sn_ = ((IT) + 3) & 3;                                     \
            GLDS16(gB0 + ((IT) + 3) * 32, &Bs[sn_][w * 512]);                   \
            GLDS16(gB1 + ((IT) + 3) * 32, &Bs[sn_][4096 + w * 512]);            \
        }                                                                       \
        __builtin_amdgcn_s_setprio(1);                                          \
        _Pragma("unroll")                                                       \
        for (int mf = 0; mf < 4; mf++)                                          \
            _Pragma("unroll")                                                   \
            for (int nf = 0; nf < 4; nf++)                                      \
                acc[4 + mf][nf] = __builtin_amdgcn_mfma_f32_16x16x32_bf16(      \
                    afr[mf], bfr[nf], acc[4 + mf][nf], 0, 0, 0);                \
        __builtin_amdgcn_s_setprio(0);                                          \
        asm volatile(VMWAIT ::: "memory");                                      \
        __builtin_amdgcn_s_barrier();                                           \
        __builtin_amdgcn_sched_barrier(0);                                      \
    }

    for (int it = 0; it < NT - 3; ++it)
        TILE_BODY(it, 1, "s_waitcnt vmcnt(8)");
    TILE_BODY(NT - 3, 0, "s_waitcnt vmcnt(4)");
    TILE_BODY(NT - 2, 0, "s_waitcnt vmcnt(0)");
    TILE_BODY(NT - 1, 0, "s_waitcnt vmcnt(0)");
#undef TILE_BODY

    // epilogue: bf16 C write
#pragma unroll
    for (int mf = 0; mf < 8; mf++) {
#pragma unroll
        for (int nf = 0; nf < 4; nf++) {
#pragma unroll
            for (int r = 0; r < 4; r++) {
                int m = m0 + wm * 128 + mf * 16 + quad * 4 + r;
                int n = n0 + wn * 64 + nf * 16 + l16;
                C[(size_t)m * N + n] = f2bf(acc[mf][nf][r]);
            }
        }
    }
}

// ---------- fused RoPE split + V transpose, bf16 qkv input ----------
__global__ __launch_bounds__(256)
void ropevt(const unsigned short* __restrict__ qkv,
            unsigned short* __restrict__ qb, unsigned short* __restrict__ kb,
            unsigned short* __restrict__ vtb) {
    __shared__ unsigned short tile[64][72];   // V slice, bf16
    const int tid = threadIdx.x;
    const int bh  = blockIdx.y;
    const int b = bh >> 4, h = bh & 15;
    const int t0 = blockIdx.x * 64;

    // ---- RoPE for q,k: 64 rows x 32 pairs = 2048 pairs, 8 per thread ----
    const float QS = 0.18033688f;   // 0.125 * log2(e)
#pragma unroll
    for (int rep = 0; rep < 8; rep++) {
        int idx  = rep * 256 + tid;
        int p    = idx & 31;
        int trow = idx >> 5;
        int t    = t0 + trow;

        size_t src = (size_t)(b * TT + t) * 3072 + h * 64 + 2 * p;
        ushort2 qu = *(const ushort2*)(qkv + src);
        ushort2 ku = *(const ushort2*)(qkv + src + 1024);
        float qx = bf2f(qu.x), qy = bf2f(qu.y);
        float kx = bf2f(ku.x), ky = bf2f(ku.y);

        float invf = __powf(10000.f, -((float)(2 * p)) / 64.f);
        float ang  = (float)t * invf;
        float sn, cs;
        __sincosf(ang, &sn, &cs);

        size_t dst = ((size_t)bh * TT + t) * 64 + 2 * p;
        ushort2 qo, ko;
        qo.x = f2bf((qx * cs - qy * sn) * QS); qo.y = f2bf((qy * cs + qx * sn) * QS);
        ko.x = f2bf(kx * cs - ky * sn); ko.y = f2bf(ky * cs + kx * sn);
        *(ushort2*)(qb + dst) = qo;
        *(ushort2*)(kb + dst) = ko;
    }

    // ---- V transpose (bf16 in, f16 out) ----
    const int row = tid >> 2;
    const unsigned short* src = qkv + ((size_t)(b * TT) + t0 + row) * 3072 + 2048 + h * 64;
    {
        int cb = (tid & 3) * 16;                        // 16 cols per thread
        ushort8 v0 = *(const ushort8*)(src + cb);
        ushort8 v1 = *(const ushort8*)(src + cb + 8);
#pragma unroll
        for (int i = 0; i < 8; i++) tile[row][cb + i] = v0[i];
#pragma unroll
        for (int i = 0; i < 8; i++) tile[row][cb + 8 + i] = v1[i];
    }
    __syncthreads();

    const int d  = tid >> 2;
    const int tc = tid & 3;
    const int hs = (d & 1) * 4;       // half-swap for odd rows
    ushort8 o0, o1;
#pragma unroll
    for (int i = 0; i < 8; i++) {
        _Float16 hv = (_Float16)bf2f(tile[tc * 16 + (i ^ hs)][d]);
        o0[i] = __builtin_bit_cast(unsigned short, hv);
    }
#pragma unroll
    for (int i = 0; i < 8; i++) {
        _Float16 hv = (_Float16)bf2f(tile[tc * 16 + 8 + (i ^ hs)][d]);
        o1[i] = __builtin_bit_cast(unsigned short, hv);
    }
    unsigned short* dst = vtb + ((size_t)bh * 64 + d) * TT + t0 + tc * 16;
    *(ushort8*)(dst) = o0;
    *(ushort8*)(dst + 8) = o1;
}

// ---------- MFMA flash attention (causal) ----------
// v2: 3-slot LDS ring, depth-2 prefetch, raw s_barrier + counted vmcnt(4)
// (never 0 mid-loop). Kills the per-iteration __syncthreads vmcnt(0) drain.
// Hazards: stage of tile it+2 targets slot (it+2)%3 == (it-1)%3 whose readers
// all passed the barrier ending iter it-1; end-of-iter vmcnt(4)+barrier proves
// tile it+1 (4 loads/wave, FIFO-oldest) landed for all waves.
__global__ __launch_bounds__(256, 3)
void attn_mfma(const unsigned short* __restrict__ qb,
               const unsigned short* __restrict__ kb,
               const unsigned short* __restrict__ vtb,
               unsigned short* __restrict__ out) {
    __shared__ unsigned short Ks[3][64 * 64];   // [t][d] bf16, chunk-swizzled
    __shared__ unsigned short Vs[3][64 * 64];   // [d][t] f16,  chunk-swizzled + half-swapped

    const int tid  = threadIdx.x;
    const int lane = tid & 63;
    const int w    = tid >> 6;
    const int quad = lane >> 4;
    const int l16  = lane & 15;

    const int bh    = blockIdx.x;                    // head pinned to one XCD (32 % 8)
    const int qtile = gridDim.y - 1 - blockIdx.y;    // longest first
    const int q0    = qtile * 64;

    const unsigned short* Qp = qb + ((size_t)bh * TT + q0 + w * 16) * 64;
    const unsigned short* Kp = kb + (size_t)bh * TT * 64;
    const unsigned short* Vp = vtb + (size_t)bh * 64 * TT;   // f16 bits in ushort

    short8 aq[2];
#pragma unroll
    for (int ks = 0; ks < 2; ks++)
        aq[ks] = *(const short8*)(Qp + (size_t)l16 * 64 + ks * 32 + quad * 8);

    floatx4 Oacc[4];   // O^T: row d = dt*16 + quad*4 + r, col q = l16
#pragma unroll
    for (int dt = 0; dt < 4; dt++) Oacc[dt] = (floatx4){0.f, 0.f, 0.f, 0.f};
    float m = -1e30f, l = 0.f;

    const int ntiles = qtile + 1;

#define STAGE(IT, P)                                                                      \
    {                                                                                     \
        const int j0s = (IT) * 64;                                                        \
        _Pragma("unroll")                                                                 \
        for (int rep = 0; rep < 2; rep++) {                                               \
            int c    = rep * 256 + tid;                                                   \
            int row  = c >> 3, sl = c & 7;                                                \
            GLDS16(Kp + (size_t)(j0s + row) * 64 + (sl ^ (row & 7)) * 8, &Ks[P][c * 8]);  \
            GLDS16(Vp + (size_t)row * TT + j0s + (sl ^ ((row >> 1) & 7)) * 8,             \
                   &Vs[P][c * 8]);                                                        \
        }                                                                                 \
    }

    // prologue: depth-2 prefetch
    STAGE(0, 0);
    if (ntiles > 1) {
        STAGE(1, 1);
        asm volatile("s_waitcnt vmcnt(4)" ::: "memory");   // tile 0 landed
    } else {
        asm volatile("s_waitcnt vmcnt(0)" ::: "memory");
    }
    __builtin_amdgcn_s_barrier();
    __builtin_amdgcn_sched_barrier(0);

    const int ksw = l16 & 7;
    const int vsw = (l16 >> 1) & 7;
    const int vsub = ((quad & 1) ^ (l16 & 1)) * 4;

    for (int it = 0; it < ntiles; ++it) {
        const int p = it % 3;
        if (it + 2 < ntiles) STAGE(it + 2, (it + 2) % 3);

        floatx4 sacc[4];
#pragma unroll
        for (int nt = 0; nt < 4; nt++) sacc[nt] = (floatx4){0.f, 0.f, 0.f, 0.f};
#pragma unroll
        for (int ks = 0; ks < 2; ks++)
#pragma unroll
            for (int nt = 0; nt < 4; nt++) {
                short8 kf = *(const short8*)&Ks[p][(nt * 16 + l16) * 64 + ((ks * 4 + quad) ^ ksw) * 8];
                sacc[nt] = __builtin_amdgcn_mfma_f32_16x16x32_bf16(kf, aq[ks], sacc[nt], 0, 0, 0);
            }

        if (it == qtile) {
            const int qg = w * 16 + l16;
#pragma unroll
            for (int nt = 0; nt < 4; nt++)
#pragma unroll
                for (int r = 0; r < 4; r++)
                    if (nt * 16 + quad * 4 + r > qg) sacc[nt][r] = -1e30f;
        }

        float mx = sacc[0][0];
#pragma unroll
        for (int nt = 0; nt < 4; nt++)
#pragma unroll
            for (int r = 0; r < 4; r++) mx = fmaxf(mx, sacc[nt][r]);
        mx = fmaxf(mx, __shfl_xor(mx, 16));
        mx = fmaxf(mx, __shfl_xor(mx, 32));
        float mnew  = fmaxf(m, mx);
        float alpha = __builtin_amdgcn_exp2f(m - mnew);
        m = mnew;
        float psum = 0.f;
#pragma unroll
        for (int nt = 0; nt < 4; nt++)
#pragma unroll
            for (int r = 0; r < 4; r++) {
                float pv = __builtin_amdgcn_exp2f(sacc[nt][r] - mnew);
                sacc[nt][r] = pv;
                psum += pv;
            }
        psum += __shfl_xor(psum, 16);
        psum += __shfl_xor(psum, 32);
        l = l * alpha + psum;

#pragma unroll
        for (int dt = 0; dt < 4; dt++)
#pragma unroll
            for (int r = 0; r < 4; r++) Oacc[dt][r] *= alpha;

        half4 bp[4];
#pragma unroll
        for (int nt = 0; nt < 4; nt++) {
            half4 h;
            h[0] = (_Float16)sacc[nt][0];
            h[1] = (_Float16)sacc[nt][1];
            h[2] = (_Float16)sacc[nt][2];
            h[3] = (_Float16)sacc[nt][3];
            bp[nt] = h;
        }

#pragma unroll
        for (int dt = 0; dt < 4; dt++)
#pragma unroll
            for (int nt = 0; nt < 4; nt++) {
                int c = nt * 2 + (quad >> 1);
                half4 vf = *(const half4*)&Vs[p][(dt * 16 + l16) * 64 + (c ^ vsw) * 8 + vsub];
                Oacc[dt] = MFMA_PV(vf, bp[nt], Oacc[dt]);
            }

        if (it + 1 < ntiles) {
            if (it + 2 < ntiles) {
                asm volatile("s_waitcnt vmcnt(4)" ::: "memory");   // it+1 landed
            } else {
                asm volatile("s_waitcnt vmcnt(0)" ::: "memory");
            }
            __builtin_amdgcn_s_barrier();
            __builtin_amdgcn_sched_barrier(0);
        }
    }
#undef STAGE

    const int b = bh >> 4, h = bh & 15;
    const float inv = 1.f / l;
    const size_t base = ((size_t)(b * TT + q0 + w * 16 + l16)) * DMODEL + h * 64 + quad * 4;
#pragma unroll
    for (int dt = 0; dt < 4; dt++) {
        ushort4 pk;
        pk.x = f2bf(Oacc[dt][0] * inv);
        pk.y = f2bf(Oacc[dt][1] * inv);
        pk.z = f2bf(Oacc[dt][2] * inv);
        pk.w = f2bf(Oacc[dt][3] * inv);
        *(ushort4*)(out + base + dt * 16) = pk;
    }
}

// ---------- launch ----------
extern "C" void kernel_launch(void* const* d_in, const int* in_sizes, int n_in,
                              void* d_out, int out_size, void* d_ws, size_t ws_size,
                              hipStream_t stream) {
    const float* x     = (const float*)d_in[0];   // [2,2048,1024]
    const float* w_qkv = (const float*)d_in[1];   // [3072,1024]
    const float* w_out = (const float*)d_in[2];   // [1024,1024]
    float* out = (float*)d_out;                   // [2,2048,1024]

    char* ws = (char*)d_ws;

    unsigned short* xb   = (unsigned short*)(ws);                 // 8 MB
    unsigned short* wqb  = (unsigned short*)(ws + 8388608);       // 6 MB
    unsigned short* wob  = (unsigned short*)(ws + 14680064);      // 2 MB
    unsigned short* qkvb = (unsigned short*)(ws + 16777216);      // 24 MB (bf16)
    unsigned short* qb   = (unsigned short*)(ws + 41943040);      // 8 MB
    unsigned short* kb   = (unsigned short*)(ws + 50331648);      // 8 MB
    unsigned short* vtb  = (unsigned short*)(ws + 58720256);      // 8 MB (f16)
    unsigned short* attb = (unsigned short*)(ws + 67108864);      // 8 MB

    castk3<<<8192, 256, 0, stream>>>(x, xb, w_qkv, wqb, w_out, wob);

    // qkv = x @ w_qkv^T   (M=4096, N=3072, K=1024), bf16 output
    gemm256<<<dim3(3072 / 256, 4096 / 256), 512, 0, stream>>>(
        xb, wqb, qkvb, 4096, 3072, 1024);

    // fused rope + v-transpose (bf16 input)
    ropevt<<<dim3(TT / 64, BB * NHEADS), 256, 0, stream>>>(qkvb, qb, kb, vtb);

    // grid: x = bh (XCD locality), y = qtile (reversed in kernel: longest first)
    attn_mfma<<<dim3(BB * NHEADS, TT / 64), 256, 0, stream>>>(qb, kb, vtb, attb);

    // out = attn @ w_out^T (M=4096, N=1024, K=1024), fp32 output
    gemm_bt<float><<<dim3(1024 / 128, 4096 / 128), 256, 0, stream>>>(
        attb, wob, out, 4096, 1024, 1024);
}

// Round 3
// 188.312 us; speedup vs baseline: 1.0431x; 1.0193x over previous
//
#include <hip/hip_runtime.h>
#include <cstdint>
#include <cstddef>

// Problem constants
#define BB 2
#define TT 2048
#define DMODEL 1024
#define NHEADS 16
#define DK 64

typedef short short8 __attribute__((ext_vector_type(8)));
typedef unsigned short ushort8 __attribute__((ext_vector_type(8)));
typedef float floatx4 __attribute__((ext_vector_type(4)));
typedef _Float16 half4 __attribute__((ext_vector_type(4)));

// gfx950 f16 MFMA 16x16x16: A/B = 4xf16 (2 VGPR), C/D = 4xf32
#define MFMA_PV(A, B, C) __builtin_amdgcn_mfma_f32_16x16x16f16(A, B, C, 0, 0, 0)

// ---------- helpers ----------
__device__ __forceinline__ unsigned short f2bf(float f) {
    uint32_t u = __builtin_bit_cast(uint32_t, f);
    uint32_t r = (u + 0x7FFFu + ((u >> 16) & 1u)) >> 16;
    return (unsigned short)r;
}
__device__ __forceinline__ float bf2f(unsigned short s) {
    uint32_t u = ((uint32_t)s) << 16;
    return __builtin_bit_cast(float, u);
}

#define GLDS16(g, l) __builtin_amdgcn_global_load_lds( \
    (const __attribute__((address_space(1))) void*)(g), \
    (__attribute__((address_space(3))) void*)(l), 16, 0, 0)

// ---------- merged cast fp32 -> bf16 for x, w_qkv, w_out (one launch) ----------
__global__ void castk3(const float* __restrict__ x, unsigned short* __restrict__ xb,
                       const float* __restrict__ wq, unsigned short* __restrict__ wqb,
                       const float* __restrict__ wo, unsigned short* __restrict__ wob) {
    int bid = blockIdx.x;
    const float* in;
    unsigned short* out;
    int base;
    if (bid < 4096)       { in = x;  out = xb;  base = bid * 1024; }
    else if (bid < 7168)  { in = wq; out = wqb; base = (bid - 4096) * 1024; }
    else                  { in = wo; out = wob; base = (bid - 7168) * 1024; }
    int i = base + threadIdx.x * 4;
    float4 v = *(const float4*)(in + i);
    ushort4 o;
    o.x = f2bf(v.x); o.y = f2bf(v.y); o.z = f2bf(v.z); o.w = f2bf(v.w);
    *(ushort4*)(out + i) = o;
}

// ---------- bf16 MFMA GEMM, C = A * B^T, BK=32 (R10-proven: 0 conflicts) ----------
// Kept for the output projection (grid 256 blocks there = 1/CU).
template <typename OUT>
__global__ __launch_bounds__(256)
void gemm_bt(const unsigned short* __restrict__ A, const unsigned short* __restrict__ B,
             OUT* __restrict__ C, int M, int N, int K) {
    __shared__ unsigned short As[128 * 32];
    __shared__ unsigned short Bs[128 * 32];

    const int tid  = threadIdx.x;
    const int lane = tid & 63;
    const int w    = tid >> 6;
    const int wm   = w & 1;
    const int wn   = w >> 1;
    const int quad = lane >> 4;
    const int l16  = lane & 15;

    const int m0 = blockIdx.y * 128;
    const int n0 = blockIdx.x * 128;

    floatx4 acc[4][4];
#pragma unroll
    for (int a = 0; a < 4; a++)
#pragma unroll
        for (int b = 0; b < 4; b++)
            acc[a][b] = (floatx4){0.f, 0.f, 0.f, 0.f};

    const int c0 = w * 128 + lane;
    const int c1 = c0 + 64;
    const int r0 = c0 >> 2, cc0 = (c0 & 3) ^ ((r0 >> 1) & 3);
    const int r1 = c1 >> 2, cc1 = (c1 & 3) ^ ((r1 >> 1) & 3);

    const unsigned short* gA0 = A + (size_t)(m0 + r0) * K + cc0 * 8;
    const unsigned short* gA1 = A + (size_t)(m0 + r1) * K + cc1 * 8;
    const unsigned short* gB0 = B + (size_t)(n0 + r0) * K + cc0 * 8;
    const unsigned short* gB1 = B + (size_t)(n0 + r1) * K + cc1 * 8;

    unsigned short* lA0 = &As[(2 * w + 0) * 512];
    unsigned short* lA1 = &As[(2 * w + 1) * 512];
    unsigned short* lB0 = &Bs[(2 * w + 0) * 512];
    unsigned short* lB1 = &Bs[(2 * w + 1) * 512];

    const int rsw = (l16 >> 1) & 3;

    for (int k0 = 0; k0 < K; k0 += 32) {
        __syncthreads();
        GLDS16(gA0 + k0, lA0);
        GLDS16(gA1 + k0, lA1);
        GLDS16(gB0 + k0, lB0);
        GLDS16(gB1 + k0, lB1);
        __syncthreads();

        short8 af[4], bf[4];
#pragma unroll
        for (int t = 0; t < 4; t++) {
            af[t] = *(const short8*)&As[(wm * 64 + t * 16 + l16) * 32 + (quad ^ rsw) * 8];
            bf[t] = *(const short8*)&Bs[(wn * 64 + t * 16 + l16) * 32 + (quad ^ rsw) * 8];
        }
#pragma unroll
        for (int tm = 0; tm < 4; tm++)
#pragma unroll
            for (int tn = 0; tn < 4; tn++)
                acc[tm][tn] = __builtin_amdgcn_mfma_f32_16x16x32_bf16(
                    af[tm], bf[tn], acc[tm][tn], 0, 0, 0);
    }

#pragma unroll
    for (int tm = 0; tm < 4; tm++) {
#pragma unroll
        for (int tn = 0; tn < 4; tn++) {
#pragma unroll
            for (int r = 0; r < 4; r++) {
                int m = m0 + wm * 64 + tm * 16 + quad * 4 + r;
                int n = n0 + wn * 64 + tn * 16 + l16;
                if constexpr (sizeof(OUT) == 4)
                    C[(size_t)m * N + n] = acc[tm][tn][r];
                else
                    C[(size_t)m * N + n] = f2bf(acc[tm][tn][r]);
            }
        }
    }
}

// ---------- 8-phase 256x256 bf16 GEMM (m201 template port), C = A * B^T ----------
// BK=64, double-buffered K-tiles, 8 waves (2M x 4N), per-wave 128x64 output.
// LDS = 2 dbuf x 2 half x [128 rows][64 cols] x {A,B} x 2B = 128 KiB exactly.
// Per K-tile: 4 phases, each {ds_read subtile ; 1 half-tile GLDS stage ;
//   barrier ; setprio(1) ; 16 MFMA ; setprio(0) ; barrier}.
// Quadrants: P1 reads A(q0)+B(q0) (12 b128), P2 B(q1) (4), P3 A(q1) (8), P4 none.
// Stage schedule (hazard-checked): P1 -> Alo(t+1), P2 -> Ahi(t+1) [other dbuf,
//   prior readers done at (t-1).P3 end-barrier]; P3 -> Blo(t+2), P4 -> Bhi(t+2)
//   [same dbuf, B-reads of tile t completed at P2 end-barrier].
// Gate: vmcnt(4) at P4 only (leaves exactly the P3/P4 stages in flight) ->
//   tile t+1 fully landed before its P1 reads. Never vmcnt(0) mid-loop.
// Chunk swizzle: row of 64 cols = 8 chunks of 16B; phys = logical ^ (row&7);
//   GLDS dest linear (chunk c -> row c>>3, slot c&7), source pre-swizzled.
//   Bank = f(phys slot) only; every frag read puts 8 lanes/slot -> conflict-free.
__global__ __launch_bounds__(512)
void gemm256(const unsigned short* __restrict__ A, const unsigned short* __restrict__ B,
             unsigned short* __restrict__ C, int M, int N, int K) {
    __shared__ unsigned short As[2][2][8192];   // [dbuf][half][128*64]
    __shared__ unsigned short Bs[2][2][8192];

    const int tid  = threadIdx.x;
    const int lane = tid & 63;
    const int w    = tid >> 6;
    const int wm   = w >> 2;          // 0..1
    const int wn   = w & 3;           // 0..3
    const int quad = lane >> 4;
    const int l16  = lane & 15;

    // XCD-aware bijective swizzle (nwg = 192, divisible by 8)
    const int gx  = gridDim.x;
    const int bid = blockIdx.y * gx + blockIdx.x;
    const int cpx = (gx * gridDim.y) >> 3;
    const int wg  = (bid & 7) * cpx + (bid >> 3);
    const int m0  = (wg / gx) * 256;
    const int n0  = (wg % gx) * 256;

    floatx4 acc[8][4];
#pragma unroll
    for (int a = 0; a < 8; a++)
#pragma unroll
        for (int b = 0; b < 4; b++)
            acc[a][b] = (floatx4){0.f, 0.f, 0.f, 0.f};

    // staging: thread handles linear chunks c=tid and c=tid+512 of each 16KiB
    // half-tile; row = c>>3 (0..127), slot = c&7, logical chunk = slot^(row&7)
    const int r1   = tid >> 3;                       // 0..63 (second load: +64)
    const int koff = ((tid & 7) ^ (r1 & 7)) * 8;     // same for both loads (64%8==0)
    const unsigned short* Ag = A + (size_t)(m0 + r1) * K + koff;
    const unsigned short* Bg = B + (size_t)(n0 + r1) * K + koff;
    const int NT2 = K >> 6;

#define STAGE_A(dd, hh, kt) { \
    GLDS16(Ag + (size_t)((hh) * 128) * K + (kt) * 64,      &As[dd][hh][tid * 8]); \
    GLDS16(Ag + (size_t)((hh) * 128 + 64) * K + (kt) * 64, &As[dd][hh][4096 + tid * 8]); }
#define STAGE_B(dd, hh, kt) { \
    GLDS16(Bg + (size_t)((hh) * 128) * K + (kt) * 64,      &Bs[dd][hh][tid * 8]); \
    GLDS16(Bg + (size_t)((hh) * 128 + 64) * K + (kt) * 64, &Bs[dd][hh][4096 + tid * 8]); }

#define BARRIER() { __builtin_amdgcn_sched_barrier(0); __builtin_amdgcn_s_barrier(); \
                    __builtin_amdgcn_sched_barrier(0); }

    // prologue: tile0 fully + Blo/Bhi(1); oldest-first order matches steady state
    STAGE_B(0, 0, 0); STAGE_B(0, 1, 0);
    STAGE_A(0, 0, 0); STAGE_A(0, 1, 0);
    STAGE_B(1, 0, 1); STAGE_B(1, 1, 1);
    asm volatile("s_waitcnt vmcnt(4)" ::: "memory");   // tile0 landed
    BARRIER();

    const int c0    = (quad ^ (l16 & 7)) * 8;   // ks=0 chunk offset; ks=1 = c0^32
    const int bhalf = wn >> 1;
    const int brow0 = (wn & 1) * 64 + l16;

    short8 a[8], b[8];

    for (int it = 0; it < NT2; ++it) {
        const int d = it & 1;

        // ---------------- P1: read A(q0)+B(q0); stage Alo(t+1) ----------------
#pragma unroll
        for (int nfl = 0; nfl < 2; nfl++)
#pragma unroll
            for (int ks = 0; ks < 2; ks++)
                b[2 * nfl + ks] = *(const short8*)&Bs[d][bhalf][(brow0 + nfl * 16) * 64 + (c0 ^ (ks * 32))];
#pragma unroll
        for (int mfl = 0; mfl < 4; mfl++)
#pragma unroll
            for (int ks = 0; ks < 2; ks++)
                a[2 * mfl + ks] = *(const short8*)&As[d][wm][(l16 + mfl * 16) * 64 + (c0 ^ (ks * 32))];
        if (it + 1 < NT2) STAGE_A(d ^ 1, 0, it + 1);
        BARRIER();
        __builtin_amdgcn_s_setprio(1);
#pragma unroll
        for (int mfl = 0; mfl < 4; mfl++)
#pragma unroll
            for (int nf = 0; nf < 2; nf++) {
                acc[mfl][nf] = __builtin_amdgcn_mfma_f32_16x16x32_bf16(a[2 * mfl], b[2 * nf], acc[mfl][nf], 0, 0, 0);
                acc[mfl][nf] = __builtin_amdgcn_mfma_f32_16x16x32_bf16(a[2 * mfl + 1], b[2 * nf + 1], acc[mfl][nf], 0, 0, 0);
            }
        __builtin_amdgcn_s_setprio(0);
        BARRIER();

        // ---------------- P2: read B(q1); stage Ahi(t+1) ----------------
#pragma unroll
        for (int nfl = 0; nfl < 2; nfl++)
#pragma unroll
            for (int ks = 0; ks < 2; ks++)
                b[4 + 2 * nfl + ks] = *(const short8*)&Bs[d][bhalf][(brow0 + 32 + nfl * 16) * 64 + (c0 ^ (ks * 32))];
        if (it + 1 < NT2) STAGE_A(d ^ 1, 1, it + 1);
        BARRIER();
        __builtin_amdgcn_s_setprio(1);
#pragma unroll
        for (int mfl = 0; mfl < 4; mfl++)
#pragma unroll
            for (int nf = 2; nf < 4; nf++) {
                acc[mfl][nf] = __builtin_amdgcn_mfma_f32_16x16x32_bf16(a[2 * mfl], b[2 * nf], acc[mfl][nf], 0, 0, 0);
                acc[mfl][nf] = __builtin_amdgcn_mfma_f32_16x16x32_bf16(a[2 * mfl + 1], b[2 * nf + 1], acc[mfl][nf], 0, 0, 0);
            }
        __builtin_amdgcn_s_setprio(0);
        BARRIER();

        // ---------------- P3: read A(q1); stage Blo(t+2) ----------------
#pragma unroll
        for (int mfl = 0; mfl < 4; mfl++)
#pragma unroll
            for (int ks = 0; ks < 2; ks++)
                a[2 * mfl + ks] = *(const short8*)&As[d][wm][(64 + l16 + mfl * 16) * 64 + (c0 ^ (ks * 32))];
        if (it + 2 < NT2) STAGE_B(d, 0, it + 2);
        BARRIER();
        __builtin_amdgcn_s_setprio(1);
#pragma unroll
        for (int mfl = 0; mfl < 4; mfl++)
#pragma unroll
            for (int nf = 0; nf < 2; nf++) {
                acc[4 + mfl][nf] = __builtin_amdgcn_mfma_f32_16x16x32_bf16(a[2 * mfl], b[2 * nf], acc[4 + mfl][nf], 0, 0, 0);
                acc[4 + mfl][nf] = __builtin_amdgcn_mfma_f32_16x16x32_bf16(a[2 * mfl + 1], b[2 * nf + 1], acc[4 + mfl][nf], 0, 0, 0);
            }
        __builtin_amdgcn_s_setprio(0);
        BARRIER();

        // ---------------- P4: stage Bhi(t+2); gate; MFMA (1,1) ----------------
        if (it + 2 < NT2) STAGE_B(d, 1, it + 2);
        if (it < NT2 - 2) {
            asm volatile("s_waitcnt vmcnt(4)" ::: "memory");   // tile t+1 landed
        } else if (it == NT2 - 2) {
            asm volatile("s_waitcnt vmcnt(0)" ::: "memory");
        }
        BARRIER();
        __builtin_amdgcn_s_setprio(1);
#pragma unroll
        for (int mfl = 0; mfl < 4; mfl++)
#pragma unroll
            for (int nf = 2; nf < 4; nf++) {
                acc[4 + mfl][nf] = __builtin_amdgcn_mfma_f32_16x16x32_bf16(a[2 * mfl], b[2 * nf], acc[4 + mfl][nf], 0, 0, 0);
                acc[4 + mfl][nf] = __builtin_amdgcn_mfma_f32_16x16x32_bf16(a[2 * mfl + 1], b[2 * nf + 1], acc[4 + mfl][nf], 0, 0, 0);
            }
        __builtin_amdgcn_s_setprio(0);
        BARRIER();
    }
#undef STAGE_A
#undef STAGE_B
#undef BARRIER

    // epilogue: bf16 C write
#pragma unroll
    for (int mf = 0; mf < 8; mf++) {
#pragma unroll
        for (int nf = 0; nf < 4; nf++) {
#pragma unroll
            for (int r = 0; r < 4; r++) {
                int m = m0 + wm * 128 + mf * 16 + quad * 4 + r;
                int n = n0 + wn * 64 + nf * 16 + l16;
                C[(size_t)m * N + n] = f2bf(acc[mf][nf][r]);
            }
        }
    }
}

// ---------- fused RoPE split + V transpose, bf16 qkv input ----------
__global__ __launch_bounds__(256)
void ropevt(const unsigned short* __restrict__ qkv,
            unsigned short* __restrict__ qb, unsigned short* __restrict__ kb,
            unsigned short* __restrict__ vtb) {
    __shared__ unsigned short tile[64][72];   // V slice, bf16
    const int tid = threadIdx.x;
    const int bh  = blockIdx.y;
    const int b = bh >> 4, h = bh & 15;
    const int t0 = blockIdx.x * 64;

    // ---- RoPE for q,k: 64 rows x 32 pairs = 2048 pairs, 8 per thread ----
    const float QS = 0.18033688f;   // 0.125 * log2(e)
#pragma unroll
    for (int rep = 0; rep < 8; rep++) {
        int idx  = rep * 256 + tid;
        int p    = idx & 31;
        int trow = idx >> 5;
        int t    = t0 + trow;

        size_t src = (size_t)(b * TT + t) * 3072 + h * 64 + 2 * p;
        ushort2 qu = *(const ushort2*)(qkv + src);
        ushort2 ku = *(const ushort2*)(qkv + src + 1024);
        float qx = bf2f(qu.x), qy = bf2f(qu.y);
        float kx = bf2f(ku.x), ky = bf2f(ku.y);

        float invf = __powf(10000.f, -((float)(2 * p)) / 64.f);
        float ang  = (float)t * invf;
        float sn, cs;
        __sincosf(ang, &sn, &cs);

        size_t dst = ((size_t)bh * TT + t) * 64 + 2 * p;
        ushort2 qo, ko;
        qo.x = f2bf((qx * cs - qy * sn) * QS); qo.y = f2bf((qy * cs + qx * sn) * QS);
        ko.x = f2bf(kx * cs - ky * sn); ko.y = f2bf(ky * cs + kx * sn);
        *(ushort2*)(qb + dst) = qo;
        *(ushort2*)(kb + dst) = ko;
    }

    // ---- V transpose (bf16 in, f16 out) ----
    const int row = tid >> 2;
    const unsigned short* src = qkv + ((size_t)(b * TT) + t0 + row) * 3072 + 2048 + h * 64;
    {
        int cb = (tid & 3) * 16;                        // 16 cols per thread
        ushort8 v0 = *(const ushort8*)(src + cb);
        ushort8 v1 = *(const ushort8*)(src + cb + 8);
#pragma unroll
        for (int i = 0; i < 8; i++) tile[row][cb + i] = v0[i];
#pragma unroll
        for (int i = 0; i < 8; i++) tile[row][cb + 8 + i] = v1[i];
    }
    __syncthreads();

    const int d  = tid >> 2;
    const int tc = tid & 3;
    const int hs = (d & 1) * 4;       // half-swap for odd rows
    ushort8 o0, o1;
#pragma unroll
    for (int i = 0; i < 8; i++) {
        _Float16 hv = (_Float16)bf2f(tile[tc * 16 + (i ^ hs)][d]);
        o0[i] = __builtin_bit_cast(unsigned short, hv);
    }
#pragma unroll
    for (int i = 0; i < 8; i++) {
        _Float16 hv = (_Float16)bf2f(tile[tc * 16 + 8 + (i ^ hs)][d]);
        o1[i] = __builtin_bit_cast(unsigned short, hv);
    }
    unsigned short* dst = vtb + ((size_t)bh * 64 + d) * TT + t0 + tc * 16;
    *(ushort8*)(dst) = o0;
    *(ushort8*)(dst + 8) = o1;
}

// ---------- MFMA flash attention (causal) ----------
// 3-slot LDS ring, depth-2 prefetch, raw s_barrier + counted vmcnt(4)
// (never 0 mid-loop) — round-1 version, improved e2e, kept as is.
__global__ __launch_bounds__(256, 3)
void attn_mfma(const unsigned short* __restrict__ qb,
               const unsigned short* __restrict__ kb,
               const unsigned short* __restrict__ vtb,
               unsigned short* __restrict__ out) {
    __shared__ unsigned short Ks[3][64 * 64];   // [t][d] bf16, chunk-swizzled
    __shared__ unsigned short Vs[3][64 * 64];   // [d][t] f16,  chunk-swizzled + half-swapped

    const int tid  = threadIdx.x;
    const int lane = tid & 63;
    const int w    = tid >> 6;
    const int quad = lane >> 4;
    const int l16  = lane & 15;

    const int bh    = blockIdx.x;                    // head pinned to one XCD (32 % 8)
    const int qtile = gridDim.y - 1 - blockIdx.y;    // longest first
    const int q0    = qtile * 64;

    const unsigned short* Qp = qb + ((size_t)bh * TT + q0 + w * 16) * 64;
    const unsigned short* Kp = kb + (size_t)bh * TT * 64;
    const unsigned short* Vp = vtb + (size_t)bh * 64 * TT;   // f16 bits in ushort

    short8 aq[2];
#pragma unroll
    for (int ks = 0; ks < 2; ks++)
        aq[ks] = *(const short8*)(Qp + (size_t)l16 * 64 + ks * 32 + quad * 8);

    floatx4 Oacc[4];   // O^T: row d = dt*16 + quad*4 + r, col q = l16
#pragma unroll
    for (int dt = 0; dt < 4; dt++) Oacc[dt] = (floatx4){0.f, 0.f, 0.f, 0.f};
    float m = -1e30f, l = 0.f;

    const int ntiles = qtile + 1;

#define STAGE(IT, P)                                                                      \
    {                                                                                     \
        const int j0s = (IT) * 64;                                                        \
        _Pragma("unroll")                                                                 \
        for (int rep = 0; rep < 2; rep++) {                                               \
            int c    = rep * 256 + tid;                                                   \
            int row  = c >> 3, sl = c & 7;                                                \
            GLDS16(Kp + (size_t)(j0s + row) * 64 + (sl ^ (row & 7)) * 8, &Ks[P][c * 8]);  \
            GLDS16(Vp + (size_t)row * TT + j0s + (sl ^ ((row >> 1) & 7)) * 8,             \
                   &Vs[P][c * 8]);                                                        \
        }                                                                                 \
    }

    // prologue: depth-2 prefetch
    STAGE(0, 0);
    if (ntiles > 1) {
        STAGE(1, 1);
        asm volatile("s_waitcnt vmcnt(4)" ::: "memory");   // tile 0 landed
    } else {
        asm volatile("s_waitcnt vmcnt(0)" ::: "memory");
    }
    __builtin_amdgcn_s_barrier();
    __builtin_amdgcn_sched_barrier(0);

    const int ksw = l16 & 7;
    const int vsw = (l16 >> 1) & 7;
    const int vsub = ((quad & 1) ^ (l16 & 1)) * 4;

    for (int it = 0; it < ntiles; ++it) {
        const int p = it % 3;
        if (it + 2 < ntiles) STAGE(it + 2, (it + 2) % 3);

        floatx4 sacc[4];
#pragma unroll
        for (int nt = 0; nt < 4; nt++) sacc[nt] = (floatx4){0.f, 0.f, 0.f, 0.f};
#pragma unroll
        for (int ks = 0; ks < 2; ks++)
#pragma unroll
            for (int nt = 0; nt < 4; nt++) {
                short8 kf = *(const short8*)&Ks[p][(nt * 16 + l16) * 64 + ((ks * 4 + quad) ^ ksw) * 8];
                sacc[nt] = __builtin_amdgcn_mfma_f32_16x16x32_bf16(kf, aq[ks], sacc[nt], 0, 0, 0);
            }

        if (it == qtile) {
            const int qg = w * 16 + l16;
#pragma unroll
            for (int nt = 0; nt < 4; nt++)
#pragma unroll
                for (int r = 0; r < 4; r++)
                    if (nt * 16 + quad * 4 + r > qg) sacc[nt][r] = -1e30f;
        }

        float mx = sacc[0][0];
#pragma unroll
        for (int nt = 0; nt < 4; nt++)
#pragma unroll
            for (int r = 0; r < 4; r++) mx = fmaxf(mx, sacc[nt][r]);
        mx = fmaxf(mx, __shfl_xor(mx, 16));
        mx = fmaxf(mx, __shfl_xor(mx, 32));
        float mnew  = fmaxf(m, mx);
        float alpha = __builtin_amdgcn_exp2f(m - mnew);
        m = mnew;
        float psum = 0.f;
#pragma unroll
        for (int nt = 0; nt < 4; nt++)
#pragma unroll
            for (int r = 0; r < 4; r++) {
                float pv = __builtin_amdgcn_exp2f(sacc[nt][r] - mnew);
                sacc[nt][r] = pv;
                psum += pv;
            }
        psum += __shfl_xor(psum, 16);
        psum += __shfl_xor(psum, 32);
        l = l * alpha + psum;

#pragma unroll
        for (int dt = 0; dt < 4; dt++)
#pragma unroll
            for (int r = 0; r < 4; r++) Oacc[dt][r] *= alpha;

        half4 bp[4];
#pragma unroll
        for (int nt = 0; nt < 4; nt++) {
            half4 h;
            h[0] = (_Float16)sacc[nt][0];
            h[1] = (_Float16)sacc[nt][1];
            h[2] = (_Float16)sacc[nt][2];
            h[3] = (_Float16)sacc[nt][3];
            bp[nt] = h;
        }

#pragma unroll
        for (int dt = 0; dt < 4; dt++)
#pragma unroll
            for (int nt = 0; nt < 4; nt++) {
                int c = nt * 2 + (quad >> 1);
                half4 vf = *(const half4*)&Vs[p][(dt * 16 + l16) * 64 + (c ^ vsw) * 8 + vsub];
                Oacc[dt] = MFMA_PV(vf, bp[nt], Oacc[dt]);
            }

        if (it + 1 < ntiles) {
            if (it + 2 < ntiles) {
                asm volatile("s_waitcnt vmcnt(4)" ::: "memory");   // it+1 landed
            } else {
                asm volatile("s_waitcnt vmcnt(0)" ::: "memory");
            }
            __builtin_amdgcn_s_barrier();
            __builtin_amdgcn_sched_barrier(0);
        }
    }
#undef STAGE

    const int b = bh >> 4, h = bh & 15;
    const float inv = 1.f / l;
    const size_t base = ((size_t)(b * TT + q0 + w * 16 + l16)) * DMODEL + h * 64 + quad * 4;
#pragma unroll
    for (int dt = 0; dt < 4; dt++) {
        ushort4 pk;
        pk.x = f2bf(Oacc[dt][0] * inv);
        pk.y = f2bf(Oacc[dt][1] * inv);
        pk.z = f2bf(Oacc[dt][2] * inv);
        pk.w = f2bf(Oacc[dt][3] * inv);
        *(ushort4*)(out + base + dt * 16) = pk;
    }
}

// ---------- launch ----------
extern "C" void kernel_launch(void* const* d_in, const int* in_sizes, int n_in,
                              void* d_out, int out_size, void* d_ws, size_t ws_size,
                              hipStream_t stream) {
    const float* x     = (const float*)d_in[0];   // [2,2048,1024]
    const float* w_qkv = (const float*)d_in[1];   // [3072,1024]
    const float* w_out = (const float*)d_in[2];   // [1024,1024]
    float* out = (float*)d_out;                   // [2,2048,1024]

    char* ws = (char*)d_ws;

    unsigned short* xb   = (unsigned short*)(ws);                 // 8 MB
    unsigned short* wqb  = (unsigned short*)(ws + 8388608);       // 6 MB
    unsigned short* wob  = (unsigned short*)(ws + 14680064);      // 2 MB
    unsigned short* qkvb = (unsigned short*)(ws + 16777216);      // 24 MB (bf16)
    unsigned short* qb   = (unsigned short*)(ws + 41943040);      // 8 MB
    unsigned short* kb   = (unsigned short*)(ws + 50331648);      // 8 MB
    unsigned short* vtb  = (unsigned short*)(ws + 58720256);      // 8 MB (f16)
    unsigned short* attb = (unsigned short*)(ws + 67108864);      // 8 MB

    castk3<<<8192, 256, 0, stream>>>(x, xb, w_qkv, wqb, w_out, wob);

    // qkv = x @ w_qkv^T   (M=4096, N=3072, K=1024), bf16 output
    gemm256<<<dim3(3072 / 256, 4096 / 256), 512, 0, stream>>>(
        xb, wqb, qkvb, 4096, 3072, 1024);

    // fused rope + v-transpose (bf16 input)
    ropevt<<<dim3(TT / 64, BB * NHEADS), 256, 0, stream>>>(qkvb, qb, kb, vtb);

    // grid: x = bh (XCD locality), y = qtile (reversed in kernel: longest first)
    attn_mfma<<<dim3(BB * NHEADS, TT / 64), 256, 0, stream>>>(qb, kb, vtb, attb);

    // out = attn @ w_out^T (M=4096, N=1024, K=1024), fp32 output
    gemm_bt<float><<<dim3(1024 / 128, 4096 / 128), 256, 0, stream>>>(
        attb, wob, out, 4096, 1024, 1024);
}